// Round 3
// baseline (414.188 us; speedup 1.0000x reference)
//
#include <hip/hip_runtime.h>
#include <stdint.h>
#include <stddef.h>

typedef __bf16 bf16;
typedef __attribute__((ext_vector_type(8))) __bf16 bf16x8;
typedef __attribute__((ext_vector_type(4))) __bf16 bf16x4;
typedef __attribute__((ext_vector_type(4))) float f32x4;

#define L_SEQ 16384
#define DH    1024
#define DM    1024
#define NC    256
#define LC    (L_SEQ / NC)   // 64

__device__ __forceinline__ void async_copy16(const void* g, void* l) {
  __builtin_amdgcn_global_load_lds((const __attribute__((address_space(1))) void*)g,
                                   (__attribute__((address_space(3))) void*)l,
                                   16, 0, 0);
}

// ---------------- prep kernels ----------------

__global__ void k_prep_params(const float* __restrict__ nu_log,
                              const float* __restrict__ theta_log,
                              const float* __restrict__ gamma_log,
                              float* __restrict__ lam_re, float* __restrict__ lam_im,
                              float* __restrict__ lamC_re, float* __restrict__ lamC_im,
                              float* __restrict__ gamma) {
  int h = blockIdx.x * blockDim.x + threadIdx.x;
  if (h >= DH) return;
  float nu  = expf(nu_log[h]);
  float th  = expf(theta_log[h]);
  float mag = expf(-nu);
  float lr = mag * cosf(th);
  float li = mag * sinf(th);
  lam_re[h] = lr; lam_im[h] = li;
  float ar = lr, ai = li;       // lambda^64 by repeated squaring
#pragma unroll
  for (int i = 0; i < 6; ++i) {
    float nr = ar * ar - ai * ai;
    float ni = 2.f * ar * ai;
    ar = nr; ai = ni;
  }
  lamC_re[h] = ar; lamC_im[h] = ai;
  gamma[h] = expf(gamma_log[h]);
}

__global__ void k_cast_x(const float* __restrict__ x, bf16* __restrict__ xb) {
  int i = (blockIdx.x * blockDim.x + threadIdx.x) * 8;
  const float4 a = *(const float4*)(x + i);
  const float4 b = *(const float4*)(x + i + 4);
  bf16x8 v;
  v[0] = (bf16)a.x; v[1] = (bf16)a.y; v[2] = (bf16)a.z; v[3] = (bf16)a.w;
  v[4] = (bf16)b.x; v[5] = (bf16)b.y; v[6] = (bf16)b.z; v[7] = (bf16)b.w;
  *(bf16x8*)(xb + i) = v;
}

// Wcat[2H][DM]: rows 0..H-1 = B_re*gamma, rows H..2H-1 = B_im*gamma
__global__ void k_prep_w(const float* __restrict__ B_re, const float* __restrict__ B_im,
                         const float* __restrict__ gamma, bf16* __restrict__ Wcat) {
  int idx = (blockIdx.x * blockDim.x + threadIdx.x) * 4;  // over H*DM
  int h = idx / DM;
  int d = idx - h * DM;
  float g = gamma[h];
  float4 re = *(const float4*)(B_re + idx);
  float4 im = *(const float4*)(B_im + idx);
  bf16x4 vr, vi;
  vr[0] = (bf16)(re.x * g); vr[1] = (bf16)(re.y * g);
  vr[2] = (bf16)(re.z * g); vr[3] = (bf16)(re.w * g);
  vi[0] = (bf16)(im.x * g); vi[1] = (bf16)(im.y * g);
  vi[2] = (bf16)(im.z * g); vi[3] = (bf16)(im.w * g);
  *(bf16x4*)(Wcat + (size_t)h * DM + d)        = vr;
  *(bf16x4*)(Wcat + (size_t)(DH + h) * DM + d) = vi;
}

// Ccat[DM][2H]: cols 0..H-1 = C_re, cols H..2H-1 = -C_im
__global__ void k_prep_c(const float* __restrict__ C_re, const float* __restrict__ C_im,
                         bf16* __restrict__ Ccat) {
  int idx = (blockIdx.x * blockDim.x + threadIdx.x) * 4;  // over DM*DH
  int d = idx / DH;
  int k = idx - d * DH;
  float4 re = *(const float4*)(C_re + idx);
  float4 im = *(const float4*)(C_im + idx);
  bf16x4 vr, vi;
  vr[0] = (bf16)re.x; vr[1] = (bf16)re.y; vr[2] = (bf16)re.z; vr[3] = (bf16)re.w;
  vi[0] = (bf16)(-im.x); vi[1] = (bf16)(-im.y); vi[2] = (bf16)(-im.z); vi[3] = (bf16)(-im.w);
  *(bf16x4*)(Ccat + (size_t)d * (2 * DH) + k)      = vr;
  *(bf16x4*)(Ccat + (size_t)d * (2 * DH) + DH + k) = vi;
}

// ---------------- GEMM: C = A[M,K] * B[N,K]^T, bf16 in, f32 acc ----------------
// m97-style staging via global_load_lds width=16 (R1/R2 A/B showed identical numerics).
// MODE 0: store bf16 (Bu).  MODE 1: store f32 with epilogue + dp[col]*x[row,col].
template <int MODE>
__global__ __launch_bounds__(256, 2)
void k_gemm(const bf16* __restrict__ A, const bf16* __restrict__ B,
            void* __restrict__ Cout, const float* __restrict__ x,
            const float* __restrict__ dp, int K, int N) {
  __shared__ bf16 As[128 * 64];
  __shared__ bf16 Bs[128 * 64];
  const int tid  = threadIdx.x;
  const int lane = tid & 63;
  const int wave = tid >> 6;
  const int wm = wave >> 1, wn = wave & 1;
  const int quad = lane >> 4;
  const int l16  = lane & 15;
  const int m0 = blockIdx.x * 128;
  const int n0 = blockIdx.y * 128;

  f32x4 acc[4][4];
#pragma unroll
  for (int i = 0; i < 4; ++i)
#pragma unroll
    for (int j = 0; j < 4; ++j)
      acc[i][j] = f32x4{0.f, 0.f, 0.f, 0.f};

  for (int k0 = 0; k0 < K; k0 += 64) {
    __syncthreads();
#pragma unroll
    for (int q = 0; q < 4; ++q) {
      const int c = q * 256 + tid;           // 16B chunk id; row = c>>3, part = c&7
      const int row = c >> 3, b = c & 7;
      async_copy16(A + (size_t)(m0 + row) * K + k0 + b * 8, (char*)As + c * 16);
      async_copy16(B + (size_t)(n0 + row) * K + k0 + b * 8, (char*)Bs + c * 16);
    }
    __syncthreads();
#pragma unroll
    for (int kk = 0; kk < 64; kk += 32) {
      bf16x8 fa[4], fb[4];
#pragma unroll
      for (int i = 0; i < 4; ++i) {
        fa[i] = *(const bf16x8*)(As + (wm * 64 + i * 16 + l16) * 64 + kk + quad * 8);
        fb[i] = *(const bf16x8*)(Bs + (wn * 64 + i * 16 + l16) * 64 + kk + quad * 8);
      }
#pragma unroll
      for (int i = 0; i < 4; ++i)
#pragma unroll
        for (int j = 0; j < 4; ++j)
          acc[i][j] = __builtin_amdgcn_mfma_f32_16x16x32_bf16(fa[i], fb[j], acc[i][j], 0, 0, 0);
    }
  }

  const int crow0 = m0 + wm * 64 + quad * 4;
  const int ccol0 = n0 + wn * 64 + l16;
  if (MODE == 0) {
    bf16* out = (bf16*)Cout;
#pragma unroll
    for (int i = 0; i < 4; ++i)
#pragma unroll
      for (int j = 0; j < 4; ++j)
#pragma unroll
        for (int p = 0; p < 4; ++p)
          out[(size_t)(crow0 + i * 16 + p) * N + ccol0 + j * 16] = (bf16)acc[i][j][p];
  } else {
    float* out = (float*)Cout;
#pragma unroll
    for (int j = 0; j < 4; ++j) {
      const int col = ccol0 + j * 16;
      const float dpv = dp[col];
#pragma unroll
      for (int i = 0; i < 4; ++i)
#pragma unroll
        for (int p = 0; p < 4; ++p) {
          const int row = crow0 + i * 16 + p;
          out[(size_t)row * N + col] = acc[i][j][p] + dpv * x[(size_t)row * N + col];
        }
    }
  }
}

// ---------------- scan kernels ----------------
// Bu bf16 [L, 2H]: col h = re, col H+h = im.

__global__ void k_scan_local(const bf16* __restrict__ Bu,
                             const float* __restrict__ lam_re,
                             const float* __restrict__ lam_im,
                             float* __restrict__ chunk_end) {
  const int h = blockIdx.y * 256 + threadIdx.x;
  const int c = blockIdx.x;
  const float lr = lam_re[h], li = lam_im[h];
  float hr = 0.f, hi = 0.f;
  const bf16* p = Bu + (size_t)c * LC * (2 * DH) + h;
#pragma unroll 4
  for (int t = 0; t < LC; ++t) {
    float br = (float)p[0];
    float bi = (float)p[DH];
    float nr = lr * hr - li * hi + br;
    float ni = lr * hi + li * hr + bi;
    hr = nr; hi = ni;
    p += 2 * DH;
  }
  chunk_end[(size_t)c * (2 * DH) + h]      = hr;
  chunk_end[(size_t)c * (2 * DH) + DH + h] = hi;
}

// interleave==1: out_final[2h]=re, [2h+1]=im (complex viewed as float pairs)
// interleave==0: out_final[h]=re only (complex ref cast to float32 -> real part)
__global__ void k_scan_chunks(const float* __restrict__ chunk_end,
                              const float* __restrict__ lamC_re,
                              const float* __restrict__ lamC_im,
                              float* __restrict__ carry_in,
                              float* __restrict__ out_final,
                              int interleave) {
  const int h = blockIdx.x * 256 + threadIdx.x;
  const float lr = lamC_re[h], li = lamC_im[h];
  float er = 0.f, ei = 0.f;
  for (int c = 0; c < NC; ++c) {
    carry_in[(size_t)c * (2 * DH) + h]      = er;
    carry_in[(size_t)c * (2 * DH) + DH + h] = ei;
    float cr = chunk_end[(size_t)c * (2 * DH) + h];
    float ci = chunk_end[(size_t)c * (2 * DH) + DH + h];
    float nr = lr * er - li * ei + cr;
    float ni = lr * ei + li * er + ci;
    er = nr; ei = ni;
  }
  if (interleave) {
    out_final[2 * h]     = er;
    out_final[2 * h + 1] = ei;
  } else {
    out_final[h] = er;
  }
}

// In-place: Hb overwrites Bu (each element read strictly before written).
__global__ void k_scan_apply(bf16* __restrict__ Bu,
                             const float* __restrict__ lam_re,
                             const float* __restrict__ lam_im,
                             const float* __restrict__ carry_in) {
  const int h = blockIdx.y * 256 + threadIdx.x;
  const int c = blockIdx.x;
  const float lr = lam_re[h], li = lam_im[h];
  float hr = carry_in[(size_t)c * (2 * DH) + h];
  float hi = carry_in[(size_t)c * (2 * DH) + DH + h];
  bf16* p = Bu + (size_t)c * LC * (2 * DH) + h;
#pragma unroll 4
  for (int t = 0; t < LC; ++t) {
    float br = (float)p[0];
    float bi = (float)p[DH];
    float nr = lr * hr - li * hi + br;
    float ni = lr * hi + li * hr + bi;
    hr = nr; hi = ni;
    p[0]  = (bf16)hr;
    p[DH] = (bf16)hi;
    p += 2 * DH;
  }
}

// ---------------- launcher ----------------

extern "C" void kernel_launch(void* const* d_in, const int* in_sizes, int n_in,
                              void* d_out, int out_size, void* d_ws, size_t ws_size,
                              hipStream_t stream) {
  const float* inputs    = (const float*)d_in[0];
  const float* nu_log    = (const float*)d_in[1];
  const float* theta_log = (const float*)d_in[2];
  const float* gamma_log = (const float*)d_in[3];
  const float* B_re      = (const float*)d_in[4];
  const float* B_im      = (const float*)d_in[5];
  const float* C_re      = (const float*)d_in[6];
  const float* C_im      = (const float*)d_in[7];
  const float* Dp        = (const float*)d_in[8];

  char* ws = (char*)d_ws;
  float* lam_re    = (float*)(ws + 0);
  float* lam_im    = (float*)(ws + 4096);
  float* lamC_re   = (float*)(ws + 8192);
  float* lamC_im   = (float*)(ws + 12288);
  float* gamma     = (float*)(ws + 16384);
  float* chunk_end = (float*)(ws + 65536);                    //  2 MB
  float* carry_in  = (float*)(ws + 65536 + (2u << 20));       //  2 MB
  bf16*  Wcat      = (bf16*) (ws + 65536 + (4u << 20));       //  4 MB
  bf16*  Ccat      = (bf16*) (ws + 65536 + (8u << 20));       //  4 MB
  bf16*  Xb        = (bf16*) (ws + 65536 + (12u << 20));      // 32 MB
  bf16*  Bu        = (bf16*) (ws + 65536 + (44u << 20));      // 64 MB (Hb in place)

  // Resolve the complex64-output flattening convention from out_size:
  //   16778240 = 1024 + L*DM  -> complex counted as 1 elem, float32 cast (real part)
  //   16779264 = 2048 + L*DM  -> complex viewed as 2 floats, interleaved re/im
  int interleave = 1;
  int state_floats = 2048;
  if (out_size == 1024 + L_SEQ * DM) { interleave = 0; state_floats = 1024; }

  float* out_state = (float*)d_out;
  float* out_y     = (float*)d_out + state_floats;   // [L, DM] f32

  k_prep_params<<<dim3(4), dim3(256), 0, stream>>>(nu_log, theta_log, gamma_log,
                                                   lam_re, lam_im, lamC_re, lamC_im, gamma);
  k_cast_x<<<dim3((L_SEQ * DM) / 8 / 256), dim3(256), 0, stream>>>(inputs, Xb);
  k_prep_w<<<dim3((DH * DM) / 4 / 256), dim3(256), 0, stream>>>(B_re, B_im, gamma, Wcat);
  k_prep_c<<<dim3((DM * DH) / 4 / 256), dim3(256), 0, stream>>>(C_re, C_im, Ccat);

  // GEMM1: Bu[L, 2H] = Xb[L, DM] @ Wcat[2H, DM]^T
  k_gemm<0><<<dim3(L_SEQ / 128, (2 * DH) / 128), dim3(256), 0, stream>>>(
      Xb, Wcat, (void*)Bu, nullptr, nullptr, DM, 2 * DH);

  k_scan_local<<<dim3(NC, DH / 256), dim3(256), 0, stream>>>(Bu, lam_re, lam_im, chunk_end);
  k_scan_chunks<<<dim3(DH / 256), dim3(256), 0, stream>>>(chunk_end, lamC_re, lamC_im,
                                                          carry_in, out_state, interleave);
  k_scan_apply<<<dim3(NC, DH / 256), dim3(256), 0, stream>>>(Bu, lam_re, lam_im, carry_in);

  // GEMM2: out_y = Hb[L, 2H] @ Ccat[DM, 2H]^T + Dp*inputs
  k_gemm<1><<<dim3(L_SEQ / 128, DM / 128), dim3(256), 0, stream>>>(
      Bu, Ccat, (void*)out_y, inputs, Dp, 2 * DH, DM);

  (void)in_sizes; (void)n_in; (void)ws_size;
}

// Round 4
// 396.260 us; speedup vs baseline: 1.0452x; 1.0452x over previous
//
#include <hip/hip_runtime.h>
#include <stdint.h>
#include <stddef.h>

typedef __bf16 bf16;
typedef __attribute__((ext_vector_type(8))) __bf16 bf16x8;
typedef __attribute__((ext_vector_type(4))) __bf16 bf16x4;
typedef __attribute__((ext_vector_type(2))) __bf16 bf16x2;
typedef __attribute__((ext_vector_type(4))) float f32x4;
typedef __attribute__((ext_vector_type(2))) float f32x2;

#define L_SEQ 16384
#define DH    1024
#define DM    1024
#define NC    256
#define LC    (L_SEQ / NC)   // 64

__device__ __forceinline__ void async_copy16(const void* g, void* l) {
  __builtin_amdgcn_global_load_lds((const __attribute__((address_space(1))) void*)g,
                                   (__attribute__((address_space(3))) void*)l,
                                   16, 0, 0);
}

// ---------------- prep ----------------

__global__ void k_prep_params(const float* __restrict__ nu_log,
                              const float* __restrict__ theta_log,
                              float* __restrict__ lam_re, float* __restrict__ lam_im,
                              float* __restrict__ lamC_re, float* __restrict__ lamC_im) {
  int h = blockIdx.x * blockDim.x + threadIdx.x;
  if (h >= DH) return;
  float nu  = expf(nu_log[h]);
  float th  = expf(theta_log[h]);
  float mag = expf(-nu);
  float lr = mag * cosf(th);
  float li = mag * sinf(th);
  lam_re[h] = lr; lam_im[h] = li;
  float ar = lr, ai = li;       // lambda^64 by repeated squaring
#pragma unroll
  for (int i = 0; i < 6; ++i) {
    float nr = ar * ar - ai * ai;
    float ni = 2.f * ar * ai;
    ar = nr; ai = ni;
  }
  lamC_re[h] = ar; lamC_im[h] = ai;
}

// One fused elementwise dispatch: [0,8192) cast_x | [8192,9216) prep_w | [9216,10240) prep_c
#define NB_CAST 8192
#define NB_W    1024
__global__ void k_prep_all(const float* __restrict__ x, bf16* __restrict__ xb,
                           const float* __restrict__ B_re, const float* __restrict__ B_im,
                           const float* __restrict__ gamma_log, bf16* __restrict__ Wcat,
                           const float* __restrict__ C_re, const float* __restrict__ C_im,
                           bf16* __restrict__ Ccat) {
  const int b = blockIdx.x;
  if (b < NB_CAST) {
    int i = (b * 256 + (int)threadIdx.x) * 8;
    const float4 a0 = *(const float4*)(x + i);
    const float4 a1 = *(const float4*)(x + i + 4);
    bf16x8 v;
    v[0] = (bf16)a0.x; v[1] = (bf16)a0.y; v[2] = (bf16)a0.z; v[3] = (bf16)a0.w;
    v[4] = (bf16)a1.x; v[5] = (bf16)a1.y; v[6] = (bf16)a1.z; v[7] = (bf16)a1.w;
    *(bf16x8*)(xb + i) = v;
  } else if (b < NB_CAST + NB_W) {
    int idx = ((b - NB_CAST) * 256 + (int)threadIdx.x) * 4;  // over H*DM
    int h = idx / DM;
    int d = idx - h * DM;
    float g = expf(gamma_log[h]);
    float4 re = *(const float4*)(B_re + idx);
    float4 im = *(const float4*)(B_im + idx);
    bf16x4 vr, vi;
    vr[0] = (bf16)(re.x * g); vr[1] = (bf16)(re.y * g);
    vr[2] = (bf16)(re.z * g); vr[3] = (bf16)(re.w * g);
    vi[0] = (bf16)(im.x * g); vi[1] = (bf16)(im.y * g);
    vi[2] = (bf16)(im.z * g); vi[3] = (bf16)(im.w * g);
    *(bf16x4*)(Wcat + (size_t)h * DM + d)        = vr;
    *(bf16x4*)(Wcat + (size_t)(DH + h) * DM + d) = vi;
  } else {
    int idx = ((b - NB_CAST - NB_W) * 256 + (int)threadIdx.x) * 4;  // over DM*DH
    int d = idx / DH;
    int k = idx - d * DH;
    float4 re = *(const float4*)(C_re + idx);
    float4 im = *(const float4*)(C_im + idx);
    bf16x4 vr, vi;
    vr[0] = (bf16)re.x; vr[1] = (bf16)re.y; vr[2] = (bf16)re.z; vr[3] = (bf16)re.w;
    vi[0] = (bf16)(-im.x); vi[1] = (bf16)(-im.y); vi[2] = (bf16)(-im.z); vi[3] = (bf16)(-im.w);
    *(bf16x4*)(Ccat + (size_t)d * (2 * DH) + k)      = vr;
    *(bf16x4*)(Ccat + (size_t)d * (2 * DH) + DH + k) = vi;
  }
}

// ---------------- GEMM: C = A[M,K] * B[N,K]^T, bf16 in, f32 acc ----------------
// LDS XOR-swizzle: chunk (row, slot) in LDS holds global part = slot ^ (row&7).
// Staging permutes SOURCE addresses (LDS dest must stay lane-contiguous for
// global_load_lds); readers index slot = part ^ (row&7)  -> 2-way banks only.
// MODE 0: store bf16 (Bu).  MODE 1: store f32 + dp[col]*x[row,col].
template <int MODE>
__global__ __launch_bounds__(256, 3)
void k_gemm(const bf16* __restrict__ A, const bf16* __restrict__ B,
            void* __restrict__ Cout, const float* __restrict__ x,
            const float* __restrict__ dp, int K, int N) {
  __shared__ bf16 As[128 * 64];
  __shared__ bf16 Bs[128 * 64];
  const int tid  = threadIdx.x;
  const int lane = tid & 63;
  const int wave = tid >> 6;
  const int wm = wave >> 1, wn = wave & 1;
  const int quad = lane >> 4;
  const int l16  = lane & 15;
  const int m0 = blockIdx.x * 128;
  const int n0 = blockIdx.y * 128;

  f32x4 acc[4][4];
#pragma unroll
  for (int i = 0; i < 4; ++i)
#pragma unroll
    for (int j = 0; j < 4; ++j)
      acc[i][j] = f32x4{0.f, 0.f, 0.f, 0.f};

  for (int k0 = 0; k0 < K; k0 += 64) {
    __syncthreads();
#pragma unroll
    for (int q = 0; q < 4; ++q) {
      const int c = q * 256 + tid;           // LDS 16B chunk id (lane-contiguous)
      const int row = c >> 3, slot = c & 7;
      const int part = slot ^ (row & 7);     // swizzled global source part
      async_copy16(A + (size_t)(m0 + row) * K + k0 + part * 8, (char*)As + c * 16);
      async_copy16(B + (size_t)(n0 + row) * K + k0 + part * 8, (char*)Bs + c * 16);
    }
    __syncthreads();
#pragma unroll
    for (int kk = 0; kk < 64; kk += 32) {
      const int pbase = (kk >> 3);           // 0 or 4
      bf16x8 fa[4], fb[4];
#pragma unroll
      for (int i = 0; i < 4; ++i) {
        const int ra = wm * 64 + i * 16 + l16;
        const int rb = wn * 64 + i * 16 + l16;
        const int sa = (pbase + quad) ^ (ra & 7);
        const int sb = (pbase + quad) ^ (rb & 7);
        fa[i] = *(const bf16x8*)(As + ra * 64 + sa * 8);
        fb[i] = *(const bf16x8*)(Bs + rb * 64 + sb * 8);
      }
#pragma unroll
      for (int i = 0; i < 4; ++i)
#pragma unroll
        for (int j = 0; j < 4; ++j)
          acc[i][j] = __builtin_amdgcn_mfma_f32_16x16x32_bf16(fa[i], fb[j], acc[i][j], 0, 0, 0);
    }
  }

  const int crow0 = m0 + wm * 64 + quad * 4;
  const int ccol0 = n0 + wn * 64 + l16;
  if (MODE == 0) {
    bf16* out = (bf16*)Cout;
#pragma unroll
    for (int i = 0; i < 4; ++i)
#pragma unroll
      for (int j = 0; j < 4; ++j)
#pragma unroll
        for (int p = 0; p < 4; ++p)
          out[(size_t)(crow0 + i * 16 + p) * N + ccol0 + j * 16] = (bf16)acc[i][j][p];
  } else {
    float* out = (float*)Cout;
#pragma unroll
    for (int j = 0; j < 4; ++j) {
      const int col = ccol0 + j * 16;
      const float dpv = dp[col];
#pragma unroll
      for (int i = 0; i < 4; ++i)
#pragma unroll
        for (int p = 0; p < 4; ++p) {
          const int row = crow0 + i * 16 + p;
          out[(size_t)row * N + col] = acc[i][j][p] + dpv * x[(size_t)row * N + col];
        }
    }
  }
}

// ---------------- scan ----------------
// Bu bf16 [L, 2H]: col h = re, col H+h = im.
// chunk_end / carry_in: f32 [NC][2048] interleaved (re,im) pairs: [c][2h],[c][2h+1].

__global__ void k_scan_local(const bf16* __restrict__ Bu,
                             const float* __restrict__ lam_re,
                             const float* __restrict__ lam_im,
                             float* __restrict__ chunk_end) {
  const int h2 = (blockIdx.y * 256 + threadIdx.x) * 2;   // channels h2, h2+1
  const int c = blockIdx.x;
  const float lr0 = lam_re[h2],     li0 = lam_im[h2];
  const float lr1 = lam_re[h2 + 1], li1 = lam_im[h2 + 1];
  float hr0 = 0.f, hi0 = 0.f, hr1 = 0.f, hi1 = 0.f;
  const bf16* p = Bu + (size_t)c * LC * (2 * DH) + h2;
#pragma unroll 4
  for (int t = 0; t < LC; ++t) {
    bf16x2 br = *(const bf16x2*)(p);
    bf16x2 bi = *(const bf16x2*)(p + DH);
    float nr0 = lr0 * hr0 - li0 * hi0 + (float)br[0];
    float ni0 = lr0 * hi0 + li0 * hr0 + (float)bi[0];
    float nr1 = lr1 * hr1 - li1 * hi1 + (float)br[1];
    float ni1 = lr1 * hi1 + li1 * hr1 + (float)bi[1];
    hr0 = nr0; hi0 = ni0; hr1 = nr1; hi1 = ni1;
    p += 2 * DH;
  }
  *(f32x4*)(chunk_end + (size_t)c * (2 * DH) + 2 * h2) = f32x4{hr0, hi0, hr1, hi1};
}

// interleave==1: out_final[2h]=re,[2h+1]=im ; interleave==0: out_final[h]=re
__global__ void k_scan_chunks(const float* __restrict__ chunk_end,
                              const float* __restrict__ lamC_re,
                              const float* __restrict__ lamC_im,
                              float* __restrict__ carry_in,
                              float* __restrict__ out_final,
                              int interleave) {
  const int h = blockIdx.x * 256 + threadIdx.x;    // 0..1023
  const float lr = lamC_re[h], li = lamC_im[h];
  float er = 0.f, ei = 0.f;
#pragma unroll 16
  for (int c = 0; c < NC; ++c) {
    *(f32x2*)(carry_in + (size_t)c * (2 * DH) + 2 * h) = f32x2{er, ei};
    f32x2 ce = *(const f32x2*)(chunk_end + (size_t)c * (2 * DH) + 2 * h);
    float nr = lr * er - li * ei + ce[0];
    float ni = lr * ei + li * er + ce[1];
    er = nr; ei = ni;
  }
  if (interleave) {
    out_final[2 * h]     = er;
    out_final[2 * h + 1] = ei;
  } else {
    out_final[h] = er;
  }
}

// In-place: H overwrites Bu (each element read strictly before written).
__global__ void k_scan_apply(bf16* __restrict__ Bu,
                             const float* __restrict__ lam_re,
                             const float* __restrict__ lam_im,
                             const float* __restrict__ carry_in) {
  const int h2 = (blockIdx.y * 256 + threadIdx.x) * 2;
  const int c = blockIdx.x;
  const float lr0 = lam_re[h2],     li0 = lam_im[h2];
  const float lr1 = lam_re[h2 + 1], li1 = lam_im[h2 + 1];
  f32x4 cv = *(const f32x4*)(carry_in + (size_t)c * (2 * DH) + 2 * h2);
  float hr0 = cv[0], hi0 = cv[1], hr1 = cv[2], hi1 = cv[3];
  bf16* p = Bu + (size_t)c * LC * (2 * DH) + h2;
#pragma unroll 4
  for (int t = 0; t < LC; ++t) {
    bf16x2 br = *(const bf16x2*)(p);
    bf16x2 bi = *(const bf16x2*)(p + DH);
    float nr0 = lr0 * hr0 - li0 * hi0 + (float)br[0];
    float ni0 = lr0 * hi0 + li0 * hr0 + (float)bi[0];
    float nr1 = lr1 * hr1 - li1 * hi1 + (float)br[1];
    float ni1 = lr1 * hi1 + li1 * hr1 + (float)bi[1];
    hr0 = nr0; hi0 = ni0; hr1 = nr1; hi1 = ni1;
    bf16x2 wr, wi;
    wr[0] = (bf16)hr0; wr[1] = (bf16)hr1;
    wi[0] = (bf16)hi0; wi[1] = (bf16)hi1;
    *(bf16x2*)(p)      = wr;
    *(bf16x2*)(p + DH) = wi;
    p += 2 * DH;
  }
}

// ---------------- launcher ----------------

extern "C" void kernel_launch(void* const* d_in, const int* in_sizes, int n_in,
                              void* d_out, int out_size, void* d_ws, size_t ws_size,
                              hipStream_t stream) {
  const float* inputs    = (const float*)d_in[0];
  const float* nu_log    = (const float*)d_in[1];
  const float* theta_log = (const float*)d_in[2];
  const float* gamma_log = (const float*)d_in[3];
  const float* B_re      = (const float*)d_in[4];
  const float* B_im      = (const float*)d_in[5];
  const float* C_re      = (const float*)d_in[6];
  const float* C_im      = (const float*)d_in[7];
  const float* Dp        = (const float*)d_in[8];

  char* ws = (char*)d_ws;
  float* lam_re    = (float*)(ws + 0);
  float* lam_im    = (float*)(ws + 4096);
  float* lamC_re   = (float*)(ws + 8192);
  float* lamC_im   = (float*)(ws + 12288);
  float* chunk_end = (float*)(ws + 65536);                    //  2 MB
  float* carry_in  = (float*)(ws + 65536 + (2u << 20));       //  2 MB
  bf16*  Wcat      = (bf16*) (ws + 65536 + (4u << 20));       //  4 MB
  bf16*  Ccat      = (bf16*) (ws + 65536 + (8u << 20));       //  4 MB
  bf16*  Xb        = (bf16*) (ws + 65536 + (12u << 20));      // 32 MB
  bf16*  Bu        = (bf16*) (ws + 65536 + (44u << 20));      // 64 MB (H in place)

  int interleave = 1;
  int state_floats = 2048;
  if (out_size == 1024 + L_SEQ * DM) { interleave = 0; state_floats = 1024; }

  float* out_state = (float*)d_out;
  float* out_y     = (float*)d_out + state_floats;   // [L, DM] f32

  k_prep_params<<<dim3(4), dim3(256), 0, stream>>>(nu_log, theta_log,
                                                   lam_re, lam_im, lamC_re, lamC_im);
  k_prep_all<<<dim3(NB_CAST + 2 * NB_W), dim3(256), 0, stream>>>(
      inputs, Xb, B_re, B_im, gamma_log, Wcat, C_re, C_im, Ccat);

  // GEMM1: Bu[L, 2H] = Xb[L, DM] @ Wcat[2H, DM]^T
  k_gemm<0><<<dim3(L_SEQ / 128, (2 * DH) / 128), dim3(256), 0, stream>>>(
      Xb, Wcat, (void*)Bu, nullptr, nullptr, DM, 2 * DH);

  k_scan_local<<<dim3(NC, 2), dim3(256), 0, stream>>>(Bu, lam_re, lam_im, chunk_end);
  k_scan_chunks<<<dim3(4), dim3(256), 0, stream>>>(chunk_end, lamC_re, lamC_im,
                                                   carry_in, out_state, interleave);
  k_scan_apply<<<dim3(NC, 2), dim3(256), 0, stream>>>(Bu, lam_re, lam_im, carry_in);

  // GEMM2: out_y = H[L, 2H] @ Ccat[DM, 2H]^T + Dp*inputs
  k_gemm<1><<<dim3(L_SEQ / 128, DM / 128), dim3(256), 0, stream>>>(
      Bu, Ccat, (void*)out_y, inputs, Dp, 2 * DH, DM);

  (void)in_sizes; (void)n_in; (void)ws_size;
}

// Round 5
// 375.800 us; speedup vs baseline: 1.1021x; 1.0544x over previous
//
#include <hip/hip_runtime.h>
#include <stdint.h>
#include <stddef.h>

typedef __bf16 bf16;
typedef __attribute__((ext_vector_type(8))) __bf16 bf16x8;
typedef __attribute__((ext_vector_type(4))) __bf16 bf16x4;
typedef __attribute__((ext_vector_type(2))) __bf16 bf16x2;
typedef __attribute__((ext_vector_type(4))) float f32x4;
typedef __attribute__((ext_vector_type(2))) float f32x2;

#define L_SEQ 16384
#define DH    1024
#define DM    1024
#define NC    256
#define LC    (L_SEQ / NC)   // 64

__device__ __forceinline__ void async_copy16(const void* g, void* l) {
  __builtin_amdgcn_global_load_lds((const __attribute__((address_space(1))) void*)g,
                                   (__attribute__((address_space(3))) void*)l,
                                   16, 0, 0);
}

// ---------------- fused prep ----------------
// blocks [0,8192): cast x -> bf16
// blocks [8192,9216): Wcat[2H][DM]  rows 0..H-1 = B_re*exp(gamma), H..2H-1 = B_im*exp(gamma)
// blocks [9216,10240): Ccat[DM][2H] cols 0..H-1 = C_re, H..2H-1 = -C_im
// blocks [10240,10244): lambda, lambda^64 per channel
#define NB_CAST 8192
#define NB_W    1024
__global__ void k_prep_all(const float* __restrict__ x, bf16* __restrict__ xb,
                           const float* __restrict__ B_re, const float* __restrict__ B_im,
                           const float* __restrict__ gamma_log, bf16* __restrict__ Wcat,
                           const float* __restrict__ C_re, const float* __restrict__ C_im,
                           bf16* __restrict__ Ccat,
                           const float* __restrict__ nu_log,
                           const float* __restrict__ theta_log,
                           float* __restrict__ lam_re, float* __restrict__ lam_im,
                           float* __restrict__ lamC_re, float* __restrict__ lamC_im) {
  const int b = blockIdx.x;
  if (b < NB_CAST) {
    int i = (b * 256 + (int)threadIdx.x) * 8;
    const float4 a0 = *(const float4*)(x + i);
    const float4 a1 = *(const float4*)(x + i + 4);
    bf16x8 v;
    v[0] = (bf16)a0.x; v[1] = (bf16)a0.y; v[2] = (bf16)a0.z; v[3] = (bf16)a0.w;
    v[4] = (bf16)a1.x; v[5] = (bf16)a1.y; v[6] = (bf16)a1.z; v[7] = (bf16)a1.w;
    *(bf16x8*)(xb + i) = v;
  } else if (b < NB_CAST + NB_W) {
    int idx = ((b - NB_CAST) * 256 + (int)threadIdx.x) * 4;  // over H*DM
    int h = idx / DM;
    int d = idx - h * DM;
    float g = expf(gamma_log[h]);
    float4 re = *(const float4*)(B_re + idx);
    float4 im = *(const float4*)(B_im + idx);
    bf16x4 vr, vi;
    vr[0] = (bf16)(re.x * g); vr[1] = (bf16)(re.y * g);
    vr[2] = (bf16)(re.z * g); vr[3] = (bf16)(re.w * g);
    vi[0] = (bf16)(im.x * g); vi[1] = (bf16)(im.y * g);
    vi[2] = (bf16)(im.z * g); vi[3] = (bf16)(im.w * g);
    *(bf16x4*)(Wcat + (size_t)h * DM + d)        = vr;
    *(bf16x4*)(Wcat + (size_t)(DH + h) * DM + d) = vi;
  } else if (b < NB_CAST + 2 * NB_W) {
    int idx = ((b - NB_CAST - NB_W) * 256 + (int)threadIdx.x) * 4;  // over DM*DH
    int d = idx / DH;
    int k = idx - d * DH;
    float4 re = *(const float4*)(C_re + idx);
    float4 im = *(const float4*)(C_im + idx);
    bf16x4 vr, vi;
    vr[0] = (bf16)re.x; vr[1] = (bf16)re.y; vr[2] = (bf16)re.z; vr[3] = (bf16)re.w;
    vi[0] = (bf16)(-im.x); vi[1] = (bf16)(-im.y); vi[2] = (bf16)(-im.z); vi[3] = (bf16)(-im.w);
    *(bf16x4*)(Ccat + (size_t)d * (2 * DH) + k)      = vr;
    *(bf16x4*)(Ccat + (size_t)d * (2 * DH) + DH + k) = vi;
  } else {
    int h = (b - NB_CAST - 2 * NB_W) * 256 + (int)threadIdx.x;
    if (h < DH) {
      float nu  = expf(nu_log[h]);
      float th  = expf(theta_log[h]);
      float mag = expf(-nu);
      float lr = mag * cosf(th);
      float li = mag * sinf(th);
      lam_re[h] = lr; lam_im[h] = li;
      float ar = lr, ai = li;       // lambda^64 by repeated squaring
#pragma unroll
      for (int i = 0; i < 6; ++i) {
        float nr = ar * ar - ai * ai;
        float ni = 2.f * ar * ai;
        ar = nr; ai = ni;
      }
      lamC_re[h] = ar; lamC_im[h] = ai;
    }
  }
}

// ---------------- GEMM: C = A[M,K] * B[N,K]^T, bf16 in, f32 acc ----------------
// LDS XOR-swizzle (bank-conflict-free, verified R4: SQ_LDS_BANK_CONFLICT=0).
// Supertile block swizzle: windows of 8 M-tiles x all N-tiles for L2 locality.
// MODE 0: store bf16 (Bu).  MODE 1: store f32 + dp[col]*x[row,col].
template <int MODE>
__global__ __launch_bounds__(256, 3)
void k_gemm(const bf16* __restrict__ A, const bf16* __restrict__ B,
            void* __restrict__ Cout, const float* __restrict__ x,
            const float* __restrict__ dp, int K, int N) {
  __shared__ bf16 As[128 * 64];
  __shared__ bf16 Bs[128 * 64];
  const int tid  = threadIdx.x;
  const int lane = tid & 63;
  const int wave = tid >> 6;
  const int wm = wave >> 1, wn = wave & 1;
  const int quad = lane >> 4;
  const int l16  = lane & 15;

  // supertile rasterization: 8 consecutive m-tiles share the window with all n-tiles
  const int lin = blockIdx.y * gridDim.x + blockIdx.x;
  const int nY  = gridDim.y;
  const int per = 8 * nY;
  const int sg  = lin / per;
  const int r   = lin - sg * per;
  const int bx  = sg * 8 + (r & 7);
  const int by  = r >> 3;
  const int m0 = bx * 128;
  const int n0 = by * 128;

  f32x4 acc[4][4];
#pragma unroll
  for (int i = 0; i < 4; ++i)
#pragma unroll
    for (int j = 0; j < 4; ++j)
      acc[i][j] = f32x4{0.f, 0.f, 0.f, 0.f};

  for (int k0 = 0; k0 < K; k0 += 64) {
    __syncthreads();
#pragma unroll
    for (int q = 0; q < 4; ++q) {
      const int c = q * 256 + tid;           // LDS 16B chunk id (lane-contiguous)
      const int row = c >> 3, slot = c & 7;
      const int part = slot ^ (row & 7);     // swizzled global source part
      async_copy16(A + (size_t)(m0 + row) * K + k0 + part * 8, (char*)As + c * 16);
      async_copy16(B + (size_t)(n0 + row) * K + k0 + part * 8, (char*)Bs + c * 16);
    }
    __syncthreads();
#pragma unroll
    for (int kk = 0; kk < 64; kk += 32) {
      const int pbase = (kk >> 3);           // 0 or 4
      bf16x8 fa[4], fb[4];
#pragma unroll
      for (int i = 0; i < 4; ++i) {
        const int ra = wm * 64 + i * 16 + l16;
        const int rb = wn * 64 + i * 16 + l16;
        const int sa = (pbase + quad) ^ (ra & 7);
        const int sb = (pbase + quad) ^ (rb & 7);
        fa[i] = *(const bf16x8*)(As + ra * 64 + sa * 8);
        fb[i] = *(const bf16x8*)(Bs + rb * 64 + sb * 8);
      }
#pragma unroll
      for (int i = 0; i < 4; ++i)
#pragma unroll
        for (int j = 0; j < 4; ++j)
          acc[i][j] = __builtin_amdgcn_mfma_f32_16x16x32_bf16(fa[i], fb[j], acc[i][j], 0, 0, 0);
    }
  }

  const int crow0 = m0 + wm * 64 + quad * 4;
  const int ccol0 = n0 + wn * 64 + l16;
  if (MODE == 0) {
    bf16* out = (bf16*)Cout;
#pragma unroll
    for (int i = 0; i < 4; ++i)
#pragma unroll
      for (int j = 0; j < 4; ++j)
#pragma unroll
        for (int p = 0; p < 4; ++p)
          out[(size_t)(crow0 + i * 16 + p) * N + ccol0 + j * 16] = (bf16)acc[i][j][p];
  } else {
    float* out = (float*)Cout;
#pragma unroll
    for (int j = 0; j < 4; ++j) {
      const int col = ccol0 + j * 16;
      const float dpv = dp[col];
#pragma unroll
      for (int i = 0; i < 4; ++i)
#pragma unroll
        for (int p = 0; p < 4; ++p) {
          const int row = crow0 + i * 16 + p;
          out[(size_t)row * N + col] = acc[i][j][p] + dpv * x[(size_t)row * N + col];
        }
    }
  }
}

// ---------------- scan ----------------
// Bu bf16 [L, 2H]: col h = re, col H+h = im.
// chunk_end: f32 [NC][2048] interleaved (re,im) pairs per complex channel.

__global__ void k_scan_local(const bf16* __restrict__ Bu,
                             const float* __restrict__ lam_re,
                             const float* __restrict__ lam_im,
                             float* __restrict__ chunk_end) {
  const int h2 = (blockIdx.y * 256 + threadIdx.x) * 2;   // channels h2, h2+1
  const int c = blockIdx.x;
  const float lr0 = lam_re[h2],     li0 = lam_im[h2];
  const float lr1 = lam_re[h2 + 1], li1 = lam_im[h2 + 1];
  float hr0 = 0.f, hi0 = 0.f, hr1 = 0.f, hi1 = 0.f;
  const bf16* p = Bu + (size_t)c * LC * (2 * DH) + h2;
#pragma unroll 4
  for (int t = 0; t < LC; ++t) {
    bf16x2 br = *(const bf16x2*)(p);
    bf16x2 bi = *(const bf16x2*)(p + DH);
    float nr0 = lr0 * hr0 - li0 * hi0 + (float)br[0];
    float ni0 = lr0 * hi0 + li0 * hr0 + (float)bi[0];
    float nr1 = lr1 * hr1 - li1 * hi1 + (float)br[1];
    float ni1 = lr1 * hi1 + li1 * hr1 + (float)bi[1];
    hr0 = nr0; hi0 = ni0; hr1 = nr1; hi1 = ni1;
    p += 2 * DH;
  }
  *(f32x4*)(chunk_end + (size_t)c * (2 * DH) + 2 * h2) = f32x4{hr0, hi0, hr1, hi1};
}

// Carry computed per-block from chunk_end aggregates (independent loads, MLP-
// pipelined; chunk_end is L2/L3-resident). In-place H over Bu. Block c=NC-1
// also emits the final hidden state.
__global__ void k_scan_apply(bf16* __restrict__ Bu,
                             const float* __restrict__ lam_re,
                             const float* __restrict__ lam_im,
                             const float* __restrict__ lamC_re,
                             const float* __restrict__ lamC_im,
                             const float* __restrict__ chunk_end,
                             float* __restrict__ out_final,
                             int interleave) {
  const int h2 = (blockIdx.y * 256 + threadIdx.x) * 2;
  const int c = blockIdx.x;
  const float lr0 = lam_re[h2],     li0 = lam_im[h2];
  const float lr1 = lam_re[h2 + 1], li1 = lam_im[h2 + 1];
  const float Lr0 = lamC_re[h2],     Li0 = lamC_im[h2];
  const float Lr1 = lamC_re[h2 + 1], Li1 = lamC_im[h2 + 1];

  // carry_c = sum_{j<c} (lambda^64)^{c-1-j} * E_j   (Horner over ascending j)
  float cr0 = 0.f, ci0 = 0.f, cr1 = 0.f, ci1 = 0.f;
  const float* ce = chunk_end + 2 * h2;
  for (int j = 0; j < c; ++j) {
    f32x4 e = *(const f32x4*)(ce + (size_t)j * (2 * DH));
    float nr0 = Lr0 * cr0 - Li0 * ci0 + e[0];
    float ni0 = Lr0 * ci0 + Li0 * cr0 + e[1];
    float nr1 = Lr1 * cr1 - Li1 * ci1 + e[2];
    float ni1 = Lr1 * ci1 + Li1 * cr1 + e[3];
    cr0 = nr0; ci0 = ni0; cr1 = nr1; ci1 = ni1;
  }

  float hr0 = cr0, hi0 = ci0, hr1 = cr1, hi1 = ci1;
  bf16* p = Bu + (size_t)c * LC * (2 * DH) + h2;
#pragma unroll 4
  for (int t = 0; t < LC; ++t) {
    bf16x2 br = *(const bf16x2*)(p);
    bf16x2 bi = *(const bf16x2*)(p + DH);
    float nr0 = lr0 * hr0 - li0 * hi0 + (float)br[0];
    float ni0 = lr0 * hi0 + li0 * hr0 + (float)bi[0];
    float nr1 = lr1 * hr1 - li1 * hi1 + (float)br[1];
    float ni1 = lr1 * hi1 + li1 * hr1 + (float)bi[1];
    hr0 = nr0; hi0 = ni0; hr1 = nr1; hi1 = ni1;
    bf16x2 wr, wi;
    wr[0] = (bf16)hr0; wr[1] = (bf16)hr1;
    wi[0] = (bf16)hi0; wi[1] = (bf16)hi1;
    *(bf16x2*)(p)      = wr;
    *(bf16x2*)(p + DH) = wi;
    p += 2 * DH;
  }

  if (c == NC - 1) {
    if (interleave) {
      *(f32x2*)(out_final + 2 * h2)       = f32x2{hr0, hi0};
      *(f32x2*)(out_final + 2 * (h2 + 1)) = f32x2{hr1, hi1};
    } else {
      out_final[h2]     = hr0;
      out_final[h2 + 1] = hr1;
    }
  }
}

// ---------------- launcher ----------------

extern "C" void kernel_launch(void* const* d_in, const int* in_sizes, int n_in,
                              void* d_out, int out_size, void* d_ws, size_t ws_size,
                              hipStream_t stream) {
  const float* inputs    = (const float*)d_in[0];
  const float* nu_log    = (const float*)d_in[1];
  const float* theta_log = (const float*)d_in[2];
  const float* gamma_log = (const float*)d_in[3];
  const float* B_re      = (const float*)d_in[4];
  const float* B_im      = (const float*)d_in[5];
  const float* C_re      = (const float*)d_in[6];
  const float* C_im      = (const float*)d_in[7];
  const float* Dp        = (const float*)d_in[8];

  char* ws = (char*)d_ws;
  float* lam_re    = (float*)(ws + 0);
  float* lam_im    = (float*)(ws + 4096);
  float* lamC_re   = (float*)(ws + 8192);
  float* lamC_im   = (float*)(ws + 12288);
  float* chunk_end = (float*)(ws + 65536);                    //  2 MB
  bf16*  Wcat      = (bf16*) (ws + 65536 + (4u << 20));       //  4 MB
  bf16*  Ccat      = (bf16*) (ws + 65536 + (8u << 20));       //  4 MB
  bf16*  Xb        = (bf16*) (ws + 65536 + (12u << 20));      // 32 MB
  bf16*  Bu        = (bf16*) (ws + 65536 + (44u << 20));      // 64 MB (H in place)

  int interleave = 1;
  int state_floats = 2048;
  if (out_size == 1024 + L_SEQ * DM) { interleave = 0; state_floats = 1024; }

  float* out_state = (float*)d_out;
  float* out_y     = (float*)d_out + state_floats;   // [L, DM] f32

  k_prep_all<<<dim3(NB_CAST + 2 * NB_W + 4), dim3(256), 0, stream>>>(
      inputs, Xb, B_re, B_im, gamma_log, Wcat, C_re, C_im, Ccat,
      nu_log, theta_log, lam_re, lam_im, lamC_re, lamC_im);

  // GEMM1: Bu[L, 2H] = Xb[L, DM] @ Wcat[2H, DM]^T
  k_gemm<0><<<dim3(L_SEQ / 128, (2 * DH) / 128), dim3(256), 0, stream>>>(
      Xb, Wcat, (void*)Bu, nullptr, nullptr, DM, 2 * DH);

  k_scan_local<<<dim3(NC, 2), dim3(256), 0, stream>>>(Bu, lam_re, lam_im, chunk_end);
  k_scan_apply<<<dim3(NC, 2), dim3(256), 0, stream>>>(Bu, lam_re, lam_im, lamC_re, lamC_im,
                                                      chunk_end, out_state, interleave);

  // GEMM2: out_y = H[L, 2H] @ Ccat[DM, 2H]^T + Dp*inputs
  k_gemm<1><<<dim3(L_SEQ / 128, DM / 128), dim3(256), 0, stream>>>(
      Bu, Ccat, (void*)out_y, inputs, Dp, 2 * DH, DM);

  (void)in_sizes; (void)n_in; (void)ws_size;
}

// Round 6
// 375.708 us; speedup vs baseline: 1.1024x; 1.0002x over previous
//
#include <hip/hip_runtime.h>
#include <stdint.h>
#include <stddef.h>

typedef __bf16 bf16;
typedef __attribute__((ext_vector_type(8))) __bf16 bf16x8;
typedef __attribute__((ext_vector_type(4))) __bf16 bf16x4;
typedef __attribute__((ext_vector_type(2))) __bf16 bf16x2;
typedef __attribute__((ext_vector_type(4))) float f32x4;
typedef __attribute__((ext_vector_type(2))) float f32x2;

#define L_SEQ 16384
#define DH    1024
#define DM    1024
#define NH2   2048           // 2*DH, interleaved complex width
#define NC    256
#define LC    (L_SEQ / NC)   // 64

__device__ __forceinline__ void async_copy16(const void* g, void* l) {
  __builtin_amdgcn_global_load_lds((const __attribute__((address_space(1))) void*)g,
                                   (__attribute__((address_space(3))) void*)l,
                                   16, 0, 0);
}

__device__ __forceinline__ float bf_lo(uint32_t w) {
  uint32_t u = w << 16; float f; __builtin_memcpy(&f, &u, 4); return f;
}
__device__ __forceinline__ float bf_hi(uint32_t w) {
  uint32_t u = w & 0xffff0000u; float f; __builtin_memcpy(&f, &u, 4); return f;
}

// ---------------- fused prep ----------------
// Interleaved complex layout everywhere: channel h -> cols/rows (2h, 2h+1).
// blocks [0,8192): cast x -> bf16
// blocks [8192,9216): Wcat[2H][DM]: row 2h = B_re[h]*e^g, row 2h+1 = B_im[h]*e^g
// blocks [9216,10240): Ccat[DM][2H]: col 2h = C_re, col 2h+1 = -C_im
// blocks [10240,10244): lambda, lambda^64
#define NB_CAST 8192
#define NB_W    1024
__global__ void k_prep_all(const float* __restrict__ x, bf16* __restrict__ xb,
                           const float* __restrict__ B_re, const float* __restrict__ B_im,
                           const float* __restrict__ gamma_log, bf16* __restrict__ Wcat,
                           const float* __restrict__ C_re, const float* __restrict__ C_im,
                           bf16* __restrict__ Ccat,
                           const float* __restrict__ nu_log,
                           const float* __restrict__ theta_log,
                           float* __restrict__ lam_re, float* __restrict__ lam_im,
                           float* __restrict__ lamC_re, float* __restrict__ lamC_im) {
  const int b = blockIdx.x;
  if (b < NB_CAST) {
    int i = (b * 256 + (int)threadIdx.x) * 8;
    const float4 a0 = *(const float4*)(x + i);
    const float4 a1 = *(const float4*)(x + i + 4);
    bf16x8 v;
    v[0] = (bf16)a0.x; v[1] = (bf16)a0.y; v[2] = (bf16)a0.z; v[3] = (bf16)a0.w;
    v[4] = (bf16)a1.x; v[5] = (bf16)a1.y; v[6] = (bf16)a1.z; v[7] = (bf16)a1.w;
    *(bf16x8*)(xb + i) = v;
  } else if (b < NB_CAST + NB_W) {
    int idx = ((b - NB_CAST) * 256 + (int)threadIdx.x) * 4;  // over H*DM
    int h = idx / DM;
    int d = idx - h * DM;
    float g = expf(gamma_log[h]);
    float4 re = *(const float4*)(B_re + idx);
    float4 im = *(const float4*)(B_im + idx);
    bf16x4 vr, vi;
    vr[0] = (bf16)(re.x * g); vr[1] = (bf16)(re.y * g);
    vr[2] = (bf16)(re.z * g); vr[3] = (bf16)(re.w * g);
    vi[0] = (bf16)(im.x * g); vi[1] = (bf16)(im.y * g);
    vi[2] = (bf16)(im.z * g); vi[3] = (bf16)(im.w * g);
    *(bf16x4*)(Wcat + (size_t)(2 * h) * DM + d)     = vr;
    *(bf16x4*)(Wcat + (size_t)(2 * h + 1) * DM + d) = vi;
  } else if (b < NB_CAST + 2 * NB_W) {
    int idx = ((b - NB_CAST - NB_W) * 256 + (int)threadIdx.x) * 4;  // over DM*DH
    int d = idx / DH;
    int k = idx - d * DH;       // k multiple of 4
    float4 re = *(const float4*)(C_re + idx);
    float4 im = *(const float4*)(C_im + idx);
    bf16x8 v;
    v[0] = (bf16)re.x; v[1] = (bf16)(-im.x);
    v[2] = (bf16)re.y; v[3] = (bf16)(-im.y);
    v[4] = (bf16)re.z; v[5] = (bf16)(-im.z);
    v[6] = (bf16)re.w; v[7] = (bf16)(-im.w);
    *(bf16x8*)(Ccat + (size_t)d * NH2 + 2 * k) = v;
  } else {
    int h = (b - NB_CAST - 2 * NB_W) * 256 + (int)threadIdx.x;
    if (h < DH) {
      float nu  = expf(nu_log[h]);
      float th  = expf(theta_log[h]);
      float mag = expf(-nu);
      float lr = mag * cosf(th);
      float li = mag * sinf(th);
      lam_re[h] = lr; lam_im[h] = li;
      float ar = lr, ai = li;       // lambda^64 by repeated squaring
#pragma unroll
      for (int i = 0; i < 6; ++i) {
        float nr = ar * ar - ai * ai;
        float ni = 2.f * ar * ai;
        ar = nr; ai = ni;
      }
      lamC_re[h] = ar; lamC_im[h] = ai;
    }
  }
}

// ---------------- GEMM: C = A[M,K] * B[N,K]^T, bf16 in, f32 acc ----------------
// K-loop LDS XOR-swizzle (bank-conflict-free, verified R4). Supertile raster.
// MODE 0 (GEMM1): epilogue = LDS transpose tile -> coalesced bf16x8 Bu stores
//                 + per-chunk local lambda-scan -> chunk_end. (interleaved cols)
// MODE 1 (GEMM2): f32 stores + dp[col]*x[row,col].
template <int MODE>
__global__ __launch_bounds__(256, 3)
void k_gemm(const bf16* __restrict__ A, const bf16* __restrict__ B,
            void* __restrict__ Cout, const float* __restrict__ x,
            const float* __restrict__ dp,
            const float* __restrict__ lam_re, const float* __restrict__ lam_im,
            float* __restrict__ chunk_end, int K, int N) {
  __shared__ char smem[32768];
  bf16* As = (bf16*)smem;              // [128][64]
  bf16* Bs = (bf16*)(smem + 16384);    // [128][64]
  const int tid  = threadIdx.x;
  const int lane = tid & 63;
  const int wave = tid >> 6;
  const int wm = wave >> 1, wn = wave & 1;
  const int quad = lane >> 4;
  const int l16  = lane & 15;

  // supertile rasterization: 8 consecutive m-tiles share the window with all n-tiles
  const int lin = blockIdx.y * gridDim.x + blockIdx.x;
  const int nY  = gridDim.y;
  const int per = 8 * nY;
  const int sg  = lin / per;
  const int r   = lin - sg * per;
  const int bx  = sg * 8 + (r & 7);
  const int by  = r >> 3;
  const int m0 = bx * 128;
  const int n0 = by * 128;

  f32x4 acc[4][4];
#pragma unroll
  for (int i = 0; i < 4; ++i)
#pragma unroll
    for (int j = 0; j < 4; ++j)
      acc[i][j] = f32x4{0.f, 0.f, 0.f, 0.f};

  for (int k0 = 0; k0 < K; k0 += 64) {
    __syncthreads();
#pragma unroll
    for (int q = 0; q < 4; ++q) {
      const int c = q * 256 + tid;           // LDS 16B chunk id (lane-contiguous)
      const int row = c >> 3, slot = c & 7;
      const int part = slot ^ (row & 7);     // swizzled global source part
      async_copy16(A + (size_t)(m0 + row) * K + k0 + part * 8, (char*)As + c * 16);
      async_copy16(B + (size_t)(n0 + row) * K + k0 + part * 8, (char*)Bs + c * 16);
    }
    __syncthreads();
#pragma unroll
    for (int kk = 0; kk < 64; kk += 32) {
      const int pbase = (kk >> 3);           // 0 or 4
      bf16x8 fa[4], fb[4];
#pragma unroll
      for (int i = 0; i < 4; ++i) {
        const int ra = wm * 64 + i * 16 + l16;
        const int rb = wn * 64 + i * 16 + l16;
        const int sa = (pbase + quad) ^ (ra & 7);
        const int sb = (pbase + quad) ^ (rb & 7);
        fa[i] = *(const bf16x8*)(As + ra * 64 + sa * 8);
        fb[i] = *(const bf16x8*)(Bs + rb * 64 + sb * 8);
      }
#pragma unroll
      for (int i = 0; i < 4; ++i)
#pragma unroll
        for (int j = 0; j < 4; ++j)
          acc[i][j] = __builtin_amdgcn_mfma_f32_16x16x32_bf16(fa[i], fb[j], acc[i][j], 0, 0, 0);
    }
  }

  if (MODE == 0) {
    // ---- epilogue: tile -> LDS (col-group XOR swizzle), coalesced store + scan ----
    __syncthreads();                       // MFMA LDS reads complete
    bf16* T = (bf16*)smem;                 // [128][128] bf16, grp = col>>3 swizzled by row&7
#pragma unroll
    for (int i = 0; i < 4; ++i)
#pragma unroll
      for (int j = 0; j < 4; ++j) {
        const int col = wn * 64 + j * 16 + l16;
        const int grp = col >> 3, cin = col & 7;
#pragma unroll
        for (int p = 0; p < 4; ++p) {
          const int row = wm * 64 + i * 16 + quad * 4 + p;
          T[row * 128 + ((grp ^ (row & 7)) << 3) + cin] = (bf16)acc[i][j][p];
        }
      }
    __syncthreads();
    // coalesced Bu store: 2 threads/row, 64 cols each
    bf16* out = (bf16*)Cout;
    {
      const int row = tid >> 1, half = tid & 1;
#pragma unroll
      for (int o = 0; o < 8; ++o) {
        const int grp = half * 8 + o;
        bf16x8 v = *(const bf16x8*)(T + row * 128 + ((grp ^ (row & 7)) << 3));
        *(bf16x8*)(out + (size_t)(m0 + row) * N + n0 + grp * 8) = v;
      }
    }
    // local chunk scan: threads 0..127 -> (chunk ck in {0,1}) x (complex ch 0..63)
    if (tid < 128) {
      const int ck = tid >> 6;
      const int ch = tid & 63;              // local complex channel
      const int gch = (n0 >> 1) + ch;       // global complex channel
      const float lr = lam_re[gch], li = lam_im[gch];
      float hr = 0.f, hi = 0.f;
      const int waddr0 = (((ch >> 2) /*grp base*/) << 3) + ((2 * ch) & 7);
#pragma unroll 8
      for (int t = 0; t < 64; ++t) {
        const int row = ck * 64 + t;
        // complex pair (cols 2ch,2ch+1) lives in one 4B word; apply grp swizzle
        const int grpsw = ((ch >> 2) ^ (row & 7)) << 3;
        uint32_t w = *(const uint32_t*)(T + row * 128 + grpsw + ((2 * ch) & 7));
        float br = bf_lo(w), bi = bf_hi(w);
        float nr = lr * hr - li * hi + br;
        float ni = lr * hi + li * hr + bi;
        hr = nr; hi = ni;
      }
      (void)waddr0;
      *(f32x2*)(chunk_end + (size_t)(2 * bx + ck) * NH2 + n0 + 2 * ch) = f32x2{hr, hi};
    }
  } else {
    float* out = (float*)Cout;
    const int crow0 = m0 + wm * 64 + quad * 4;
    const int ccol0 = n0 + wn * 64 + l16;
#pragma unroll
    for (int j = 0; j < 4; ++j) {
      const int col = ccol0 + j * 16;
      const float dpv = dp[col];
#pragma unroll
      for (int i = 0; i < 4; ++i)
#pragma unroll
        for (int p = 0; p < 4; ++p) {
          const int row = crow0 + i * 16 + p;
          out[(size_t)row * N + col] = acc[i][j][p] + dpv * x[(size_t)row * N + col];
        }
    }
  }
}

// ---------------- carry scan over chunks (tiny, serial over NC) ----------------
// chunk_end/carry_in: f32 [NC][NH2], interleaved (re at 2h, im at 2h+1).
__global__ void k_scan_carry(const float* __restrict__ chunk_end,
                             const float* __restrict__ lamC_re,
                             const float* __restrict__ lamC_im,
                             float* __restrict__ carry_in,
                             float* __restrict__ out_final,
                             int interleave) {
  const int h = blockIdx.x * 256 + threadIdx.x;    // complex channel 0..1023
  const float lr = lamC_re[h], li = lamC_im[h];
  float er = 0.f, ei = 0.f;
#pragma unroll 16
  for (int c = 0; c < NC; ++c) {
    *(f32x2*)(carry_in + (size_t)c * NH2 + 2 * h) = f32x2{er, ei};
    f32x2 ce = *(const f32x2*)(chunk_end + (size_t)c * NH2 + 2 * h);
    float nr = lr * er - li * ei + ce[0];
    float ni = lr * ei + li * er + ce[1];
    er = nr; ei = ni;
  }
  if (interleave) {
    *(f32x2*)(out_final + 2 * h) = f32x2{er, ei};
  } else {
    out_final[h] = er;
  }
}

// ---------------- apply: H over Bu in place (interleaved complex) ----------------
__global__ void k_scan_apply(bf16* __restrict__ Bu,
                             const float* __restrict__ lam_re,
                             const float* __restrict__ lam_im,
                             const float* __restrict__ carry_in) {
  const int colbase = (blockIdx.y * 256 + (int)threadIdx.x) * 4;  // 2 complex channels
  const int c = blockIdx.x;
  const int h0 = colbase >> 1;
  const float lr0 = lam_re[h0],     li0 = lam_im[h0];
  const float lr1 = lam_re[h0 + 1], li1 = lam_im[h0 + 1];
  f32x4 cv = *(const f32x4*)(carry_in + (size_t)c * NH2 + colbase);
  float hr0 = cv[0], hi0 = cv[1], hr1 = cv[2], hi1 = cv[3];
  bf16* p = Bu + (size_t)c * LC * NH2 + colbase;
#pragma unroll 4
  for (int t = 0; t < LC; ++t) {
    bf16x4 b = *(const bf16x4*)(p);
    float nr0 = lr0 * hr0 - li0 * hi0 + (float)b[0];
    float ni0 = lr0 * hi0 + li0 * hr0 + (float)b[1];
    float nr1 = lr1 * hr1 - li1 * hi1 + (float)b[2];
    float ni1 = lr1 * hi1 + li1 * hr1 + (float)b[3];
    hr0 = nr0; hi0 = ni0; hr1 = nr1; hi1 = ni1;
    bf16x4 wv;
    wv[0] = (bf16)hr0; wv[1] = (bf16)hi0;
    wv[2] = (bf16)hr1; wv[3] = (bf16)hi1;
    *(bf16x4*)(p) = wv;
    p += NH2;
  }
}

// ---------------- launcher ----------------

extern "C" void kernel_launch(void* const* d_in, const int* in_sizes, int n_in,
                              void* d_out, int out_size, void* d_ws, size_t ws_size,
                              hipStream_t stream) {
  const float* inputs    = (const float*)d_in[0];
  const float* nu_log    = (const float*)d_in[1];
  const float* theta_log = (const float*)d_in[2];
  const float* gamma_log = (const float*)d_in[3];
  const float* B_re      = (const float*)d_in[4];
  const float* B_im      = (const float*)d_in[5];
  const float* C_re      = (const float*)d_in[6];
  const float* C_im      = (const float*)d_in[7];
  const float* Dp        = (const float*)d_in[8];

  char* ws = (char*)d_ws;
  float* lam_re    = (float*)(ws + 0);
  float* lam_im    = (float*)(ws + 4096);
  float* lamC_re   = (float*)(ws + 8192);
  float* lamC_im   = (float*)(ws + 12288);
  float* chunk_end = (float*)(ws + 65536);                    //  2 MB
  float* carry_in  = (float*)(ws + 65536 + (2u << 20));       //  2 MB
  bf16*  Wcat      = (bf16*) (ws + 65536 + (4u << 20));       //  4 MB
  bf16*  Ccat      = (bf16*) (ws + 65536 + (8u << 20));       //  4 MB
  bf16*  Xb        = (bf16*) (ws + 65536 + (12u << 20));      // 32 MB
  bf16*  Bu        = (bf16*) (ws + 65536 + (44u << 20));      // 64 MB (H in place)

  int interleave = 1;
  int state_floats = 2048;
  if (out_size == 1024 + L_SEQ * DM) { interleave = 0; state_floats = 1024; }

  float* out_state = (float*)d_out;
  float* out_y     = (float*)d_out + state_floats;   // [L, DM] f32

  k_prep_all<<<dim3(NB_CAST + 2 * NB_W + 4), dim3(256), 0, stream>>>(
      inputs, Xb, B_re, B_im, gamma_log, Wcat, C_re, C_im, Ccat,
      nu_log, theta_log, lam_re, lam_im, lamC_re, lamC_im);

  // GEMM1: Bu[L, NH2] = Xb[L, DM] @ Wcat[NH2, DM]^T, + local chunk scan -> chunk_end
  k_gemm<0><<<dim3(L_SEQ / 128, NH2 / 128), dim3(256), 0, stream>>>(
      Xb, Wcat, (void*)Bu, nullptr, nullptr, lam_re, lam_im, chunk_end, DM, NH2);

  k_scan_carry<<<dim3(4), dim3(256), 0, stream>>>(chunk_end, lamC_re, lamC_im,
                                                  carry_in, out_state, interleave);
  k_scan_apply<<<dim3(NC, 2), dim3(256), 0, stream>>>(Bu, lam_re, lam_im, carry_in);

  // GEMM2: out_y = H[L, NH2] @ Ccat[DM, NH2]^T + Dp*inputs
  k_gemm<1><<<dim3(L_SEQ / 128, DM / 128), dim3(256), 0, stream>>>(
      Bu, Ccat, (void*)out_y, inputs, Dp, nullptr, nullptr, nullptr, NH2, DM);

  (void)in_sizes; (void)n_in; (void)ws_size;
}